// Round 9
// baseline (188.372 us; speedup 1.0000x reference)
//
#include <hip/hip_runtime.h>
#include <hip/hip_bf16.h>

#define NN 4096
#define INS 512
#define HIDW 512
#define MIDW 64
#define OUTW 128
#define CAP 384   // per-row nonzero capacity (mean ~205, binomial max ~275)
#define BN_EPS 1e-5f
#define CS_BLOCKS 128
#define CS_ROWS (NN / CS_BLOCKS)   // 32 rows per colsum block
#define NSTRIP 16                  // 256-col strips per row

// ---------------------------------------------------------------------------
// K1a: per-(row,strip) active masks + counts. One wave per 256-col strip.
// Fully parallel: 65536 independent waves, no running offsets.
// ---------------------------------------------------------------------------
__global__ __launch_bounds__(256) void k_count(
    const float* __restrict__ adj,
    unsigned long long* __restrict__ msk, int* __restrict__ cnt,
    int* __restrict__ dflag)
{
    const int t = threadIdx.x;
    const int wave = t >> 6, lane = t & 63;
    const int gw = blockIdx.x * 4 + wave;
    const int i = gw >> 4, s = gw & 15;
    const int colbase = s * 256;
    float4 a4 = *reinterpret_cast<const float4*>(
        adj + (size_t)i * NN + colbase + 4 * lane);
    const float av[4] = {a4.x, a4.y, a4.z, a4.w};
    unsigned long long m[4];
    int total = 0;
    #pragma unroll
    for (int c = 0; c < 4; ++c) {
        int col = colbase + 4 * lane + c;
        bool diag = (col == i);
        bool act = (av[c] != 0.f) || diag;
        if (diag) dflag[i] = (av[c] != 0.f) ? 1 : 0;   // one lane per row hits this
        m[c] = __ballot(act);
        total += __popcll(m[c]);
    }
    if (lane == 0) {
        unsigned long long* mp = msk + (size_t)gw * 4;
        mp[0] = m[0]; mp[1] = m[1]; mp[2] = m[2]; mp[3] = m[3];
        cnt[gw] = total;
    }
}

// ---------------------------------------------------------------------------
// K1b: per-row exclusive prefix over the 16 strip counts
// ---------------------------------------------------------------------------
__global__ __launch_bounds__(256) void k_prefix(
    const int* __restrict__ cnt, int* __restrict__ off, int* __restrict__ nnz)
{
    int i = blockIdx.x * 256 + threadIdx.x;
    int run = 0;
    #pragma unroll
    for (int s = 0; s < NSTRIP; ++s) {
        off[i * NSTRIP + s] = run;
        run += cnt[i * NSTRIP + s];
    }
    nnz[i] = (run < CAP) ? run : CAP;
}

// ---------------------------------------------------------------------------
// K1c: fill CSR. One wave per strip; positions from stored bitmask (no
// ballots, no serial spine). MLP computed branch-free for all elements.
// Streams xdeg/ydeg densely; adj is NOT re-read (masks encode it).
// ---------------------------------------------------------------------------
__global__ __launch_bounds__(256) void k_fill(
    const float* __restrict__ xdeg, const float* __restrict__ ydeg,
    const unsigned long long* __restrict__ msk, const int* __restrict__ off,
    const int* __restrict__ dflag,
    const float* __restrict__ w1, const float* __restrict__ b1,
    const float* __restrict__ w2, const float* __restrict__ b2,
    float* __restrict__ a_vals, int* __restrict__ a_cols,
    float* __restrict__ rs_part)
{
    __shared__ float shb[16], sw1x[16], sw1y[16], sw2[32], sb2[2];
    const int t = threadIdx.x;
    if (t < 16) {
        shb[t]  = b1[t] + w1[t];      // fold av==1 weight row into bias
        sw1x[t] = w1[16 + t];
        sw1y[t] = w1[32 + t];
    }
    if (t < 32) sw2[t] = w2[t];
    if (t < 2)  sb2[t] = b2[t];
    __syncthreads();

    const int wave = t >> 6, lane = t & 63;
    const int gw = blockIdx.x * 4 + wave;
    const int i = gw >> 4, s = gw & 15;
    const int colbase = s * 256;
    const size_t rbase = (size_t)i * NN + colbase + 4 * lane;
    float4 x4 = *reinterpret_cast<const float4*>(xdeg + rbase);
    float4 y4 = *reinterpret_cast<const float4*>(ydeg + rbase);
    const unsigned long long* mp = msk + (size_t)gw * 4;
    unsigned long long m0 = mp[0], m1 = mp[1], m2 = mp[2], m3 = mp[3];
    const int wb = off[gw];
    const int hasde = dflag[i];

    const unsigned long long ltmask = (1ULL << lane) - 1ULL;
    int bases[4];
    bases[0] = 0;
    bases[1] = __popcll(m0);
    bases[2] = bases[1] + __popcll(m1);
    bases[3] = bases[2] + __popcll(m2);
    const unsigned long long mm[4] = {m0, m1, m2, m3};

    const float xv[4] = {x4.x, x4.y, x4.z, x4.w};
    const float yv[4] = {y4.x, y4.y, y4.z, y4.w};
    float* __restrict__ gv = a_vals + (size_t)i * CAP;
    int*   __restrict__ gc = a_cols + (size_t)i * CAP;
    float local = 0.f;
    #pragma unroll
    for (int c = 0; c < 4; ++c) {
        bool act = (mm[c] >> lane) & 1ULL;
        int col = colbase + 4 * lane + c;
        float l0 = sb2[0], l1 = sb2[1];
        #pragma unroll
        for (int w = 0; w < 16; ++w) {
            float hw = fmaf(xv[c], sw1x[w], shb[w]);
            hw = fmaf(yv[c], sw1y[w], hw);
            hw = fmaxf(hw, 0.f);
            l0 = fmaf(hw, sw2[2 * w],     l0);
            l1 = fmaf(hw, sw2[2 * w + 1], l1);
        }
        float v = 1.f / (1.f + __expf(l0 - l1));   // softmax(...)[1]
        if (col == i) v = hasde ? (v + 1.f) : 1.f;
        if (act) {
            int pos = wb + bases[c] + __popcll(mm[c] & ltmask);
            if (pos < CAP) { gc[pos] = col; gv[pos] = v; }
            local += v;
        }
    }
    #pragma unroll
    for (int o = 32; o >= 1; o >>= 1)
        local += __shfl_down(local, o, 64);
    if (lane == 0) rs_part[gw] = local;
}

// ---------------------------------------------------------------------------
// K1d: column sums of the CSR, hierarchical (LDS atomics -> dense partials)
// ---------------------------------------------------------------------------
__global__ __launch_bounds__(256) void k_colsum(
    const float* __restrict__ a_vals, const int* __restrict__ a_cols,
    const int* __restrict__ nnz, float* __restrict__ P)
{
    __shared__ float ls[NN];
    const int t = threadIdx.x;
    const int b = blockIdx.x;
    for (int j = t; j < NN; j += 256) ls[j] = 0.f;
    __syncthreads();
    const int r0 = b * CS_ROWS;
    for (int r = r0; r < r0 + CS_ROWS; ++r) {
        const int n = nnz[r];
        const float* __restrict__ vr = a_vals + (size_t)r * CAP;
        const int*   __restrict__ cr = a_cols + (size_t)r * CAP;
        for (int p = t; p < n; p += 256)
            atomicAdd(&ls[cr[p]], vr[p]);
    }
    __syncthreads();
    for (int j = t; j < NN; j += 256)
        P[(size_t)b * NN + j] = ls[j];
}

// ---------------------------------------------------------------------------
// K2: reduce partials -> degree scale factors
// ---------------------------------------------------------------------------
__global__ __launch_bounds__(256) void k_scale2(
    const float* __restrict__ rs_part, const float* __restrict__ P,
    float* __restrict__ d_row, float* __restrict__ d_col)
{
    int j = blockIdx.x * 256 + threadIdx.x;
    float r = 0.f;
    #pragma unroll
    for (int s = 0; s < NSTRIP; ++s) r += rs_part[j * NSTRIP + s];
    d_row[j] = (r > 0.f) ? 1.f / sqrtf(r) : 0.f;
    float c = 0.f;
    for (int b = 0; b < CS_BLOCKS; ++b)
        c += P[(size_t)b * NN + j];
    d_col[j] = (c > 0.f) ? 1.f / sqrtf(c) : 0.f;
}

// ---------------------------------------------------------------------------
// K3: prep — Wp = s1 ⊙rows lin2_w ;  c1 = t1@lin2_w + lin2_b ;  s2/t2 for BN2
// ---------------------------------------------------------------------------
__global__ __launch_bounds__(512) void k_prep(
    const float* __restrict__ lin2_w, const float* __restrict__ lin2_b,
    const float* __restrict__ bn1_g, const float* __restrict__ bn1_b,
    const float* __restrict__ bn1_m, const float* __restrict__ bn1_v,
    const float* __restrict__ bn2_g, const float* __restrict__ bn2_b,
    const float* __restrict__ bn2_m, const float* __restrict__ bn2_v,
    float* __restrict__ Wp, float* __restrict__ c1,
    float* __restrict__ s2g, float* __restrict__ t2g)
{
    __shared__ float t1s[HIDW];
    const int t = threadIdx.x;
    {
        int h = t;
        float s1 = bn1_g[h] * rsqrtf(bn1_v[h] + BN_EPS);
        t1s[h] = bn1_b[h] - bn1_m[h] * s1;
        for (int m = 0; m < MIDW; ++m)
            Wp[(size_t)h * MIDW + m] = s1 * lin2_w[(size_t)h * MIDW + m];
    }
    __syncthreads();
    if (t < MIDW) {
        float acc = lin2_b[t];
        for (int h = 0; h < HIDW; ++h)
            acc = fmaf(t1s[h], lin2_w[(size_t)h * MIDW + t], acc);
        c1[t] = acc;
    } else if (t >= 64 && t < 64 + OUTW) {
        int j = t - 64;
        float s2 = bn2_g[j] * rsqrtf(bn2_v[j] + BN_EPS);
        s2g[j] = s2;
        t2g[j] = bn2_b[j] - bn2_m[j] * s2;
    }
}

// ---------------------------------------------------------------------------
// K4: thin GEMM  C[M x 64] = (A[M x K] (+abias along k)) @ B[K x 64], epi rowscale
// ---------------------------------------------------------------------------
template <bool ABIAS, bool ROWSCALE>
__global__ __launch_bounds__(256) void k_thin(
    const float* __restrict__ A, const float* __restrict__ B,
    const float* __restrict__ abias, const float* __restrict__ rscale,
    float* __restrict__ C, int M, int K)
{
    __shared__ float As[64][20];   // [k][r], stride 20 -> b128-aligned reads
    __shared__ float Bs[64][64];
    const int t = threadIdx.x;
    const int bm = blockIdx.x * 16;
    const int col = t & 63, rg = t >> 6;

    float acc[4] = {0.f, 0.f, 0.f, 0.f};

    for (int k0 = 0; k0 < K; k0 += 64) {
        #pragma unroll
        for (int l = 0; l < 4; ++l) {
            int e = t + l * 256;
            int r = e >> 6, k = e & 63;
            float v = A[(size_t)(bm + r) * K + k0 + k];
            if (ABIAS) v += abias[k0 + k];
            As[k][r] = v;
        }
        #pragma unroll
        for (int l = 0; l < 16; ++l) {
            int e = t + l * 256;
            int k = e >> 6, n = e & 63;
            Bs[k][n] = B[(size_t)(k0 + k) * 64 + n];
        }
        __syncthreads();
        #pragma unroll
        for (int k = 0; k < 64; ++k) {
            float4 a4 = *reinterpret_cast<const float4*>(&As[k][rg * 4]);
            float b = Bs[k][col];
            acc[0] = fmaf(a4.x, b, acc[0]);
            acc[1] = fmaf(a4.y, b, acc[1]);
            acc[2] = fmaf(a4.z, b, acc[2]);
            acc[3] = fmaf(a4.w, b, acc[3]);
        }
        __syncthreads();
    }

    #pragma unroll
    for (int u = 0; u < 4; ++u) {
        int r = bm + rg * 4 + u;
        float x = acc[u];
        if (ROWSCALE) x *= rscale[r];
        C[(size_t)r * 64 + col] = x;
    }
}

// ---------------------------------------------------------------------------
// K5: 64-wide SpMM, 1 wave per row, 2 edges per load-inst (512 B/inst).
// ---------------------------------------------------------------------------
template <bool WITH_MID>
__global__ __launch_bounds__(64) void k_spmm64(
    const float* __restrict__ a_vals, const int* __restrict__ a_cols,
    const int* __restrict__ nnz, const float* __restrict__ X,
    const float* __restrict__ d_row, const float* __restrict__ d_col,
    const float* __restrict__ c1,
    float* __restrict__ O1, float* __restrict__ O2)
{
    __shared__ float sv[CAP];
    __shared__ int   scl[CAP];
    const int i = blockIdx.x;
    const int lane = threadIdx.x;
    const int n = nnz[i];
    const int n8 = (n + 7) & ~7;
    const float* __restrict__ vrow = a_vals + (size_t)i * CAP;
    const int*   __restrict__ crow = a_cols + (size_t)i * CAP;

    for (int p = lane; p < n8; p += 64) {
        bool ok = p < n;
        sv[p]  = ok ? vrow[p] : 0.f;
        scl[p] = ok ? crow[p] : 0;
    }
    __syncthreads();

    const int eh = lane >> 5;
    const int lc = lane & 31;
    const int npairs = n8 >> 1;

    float a0 = 0.f, a1 = 0.f;
    for (int q = 0; q < npairs; q += 4) {
        #pragma unroll
        for (int j = 0; j < 4; ++j) {
            int p = 2 * (q + j) + eh;
            float v = sv[p];
            int c = scl[p];
            float2 x = *reinterpret_cast<const float2*>(X + (size_t)c * 64 + 2 * lc);
            a0 = fmaf(v, x.x, a0);
            a1 = fmaf(v, x.y, a1);
        }
    }
    a0 += __shfl_xor(a0, 32);
    a1 += __shfl_xor(a1, 32);

    if (lane < 32) {
        float dr = d_row[i];
        if (WITH_MID) {
            float dc = d_col[i];
            float m0 = fmaf(a0, dr, c1[2 * lc]);
            float m1 = fmaf(a1, dr, c1[2 * lc + 1]);
            *reinterpret_cast<float2*>(O1 + (size_t)i * 64 + 2 * lc) =
                make_float2(m0, m1);
            *reinterpret_cast<float2*>(O2 + (size_t)i * 64 + 2 * lc) =
                make_float2(dc * fmaxf(m0, 0.f), dc * fmaxf(m1, 0.f));
        } else {
            *reinterpret_cast<float2*>(O1 + (size_t)i * 64 + 2 * lc) =
                make_float2(a0 * dr, a1 * dr);
        }
    }
}

// ---------------------------------------------------------------------------
// K6: out[4096x128] = (S[4096x64] @ gc3[64x128]) * s2 + t2
// ---------------------------------------------------------------------------
__global__ __launch_bounds__(256) void k_out(
    const float* __restrict__ S, const float* __restrict__ gc3,
    const float* __restrict__ s2g, const float* __restrict__ t2g,
    float* __restrict__ out)
{
    __shared__ float Ss[64][20];
    __shared__ float Gs[64][128];
    const int t = threadIdx.x;
    const int bm = blockIdx.x * 16;

    {
        int r = t >> 4, c4 = (t & 15) * 4;
        float4 v = *reinterpret_cast<const float4*>(S + (size_t)(bm + r) * 64 + c4);
        Ss[c4 + 0][r] = v.x; Ss[c4 + 1][r] = v.y;
        Ss[c4 + 2][r] = v.z; Ss[c4 + 3][r] = v.w;
    }
    #pragma unroll
    for (int l = 0; l < 32; ++l) {
        int e = t + l * 256;
        Gs[e >> 7][e & 127] = gc3[e];
    }
    __syncthreads();

    const int j = t & 127;
    const int r0 = (t >> 7) * 8;
    float acc[8] = {};
    #pragma unroll
    for (int k = 0; k < 64; ++k) {
        float g = Gs[k][j];
        float4 a = *reinterpret_cast<const float4*>(&Ss[k][r0]);
        float4 b = *reinterpret_cast<const float4*>(&Ss[k][r0 + 4]);
        acc[0] = fmaf(a.x, g, acc[0]); acc[1] = fmaf(a.y, g, acc[1]);
        acc[2] = fmaf(a.z, g, acc[2]); acc[3] = fmaf(a.w, g, acc[3]);
        acc[4] = fmaf(b.x, g, acc[4]); acc[5] = fmaf(b.y, g, acc[5]);
        acc[6] = fmaf(b.z, g, acc[6]); acc[7] = fmaf(b.w, g, acc[7]);
    }
    float s2 = s2g[j], t2 = t2g[j];
    #pragma unroll
    for (int u = 0; u < 8; ++u)
        out[(size_t)(bm + r0 + u) * 128 + j] = fmaf(acc[u], s2, t2);
}

// ---------------------------------------------------------------------------
extern "C" void kernel_launch(void* const* d_in, const int* in_sizes, int n_in,
                              void* d_out, int out_size, void* d_ws, size_t ws_size,
                              hipStream_t stream) {
    const float* adj    = (const float*)d_in[0];
    const float* xdeg   = (const float*)d_in[1];
    const float* ydeg   = (const float*)d_in[2];
    const float* mlp_w1 = (const float*)d_in[3];
    const float* mlp_b1 = (const float*)d_in[4];
    const float* mlp_w2 = (const float*)d_in[5];
    const float* mlp_b2 = (const float*)d_in[6];
    const float* pe_w   = (const float*)d_in[7];
    const float* pe_b   = (const float*)d_in[8];
    const float* gc1_w  = (const float*)d_in[9];
    const float* lin2_w = (const float*)d_in[10];
    const float* lin2_b = (const float*)d_in[11];
    const float* gc3_w  = (const float*)d_in[12];
    const float* bn1_g  = (const float*)d_in[13];
    const float* bn1_b  = (const float*)d_in[14];
    const float* bn1_m  = (const float*)d_in[15];
    const float* bn1_v  = (const float*)d_in[16];
    const float* bn2_g  = (const float*)d_in[17];
    const float* bn2_b  = (const float*)d_in[18];
    const float* bn2_m  = (const float*)d_in[19];
    const float* bn2_v  = (const float*)d_in[20];

    float* out = (float*)d_out;                 // [NN * OUTW]
    float* mid = out + (size_t)NN * OUTW;       // [NN * MIDW]

    char* w = (char*)d_ws;
    float* a_vals = (float*)w;  w += (size_t)NN * CAP * 4;
    int*   a_cols = (int*)w;    w += (size_t)NN * CAP * 4;
    int*   nnz    = (int*)w;    w += (size_t)NN * 4;
    unsigned long long* msk = (unsigned long long*)w; w += (size_t)NN * NSTRIP * 4 * 8;
    int*   cnt    = (int*)w;    w += (size_t)NN * NSTRIP * 4;
    int*   off    = (int*)w;    w += (size_t)NN * NSTRIP * 4;
    int*   dflag  = (int*)w;    w += (size_t)NN * 4;
    float* rs_part= (float*)w;  w += (size_t)NN * NSTRIP * 4;
    float* d_row  = (float*)w;  w += (size_t)NN * 4;
    float* d_col  = (float*)w;  w += (size_t)NN * 4;
    float* P      = (float*)w;  w += (size_t)CS_BLOCKS * NN * 4;
    float* Wp     = (float*)w;  w += (size_t)HIDW * MIDW * 4;
    float* W2     = (float*)w;  w += (size_t)INS * MIDW * 4;
    float* c1     = (float*)w;  w += 256;
    float* s2g    = (float*)w;  w += 512;
    float* t2g    = (float*)w;  w += 512;
    float* G      = (float*)w;  w += (size_t)NN * MIDW * 4;
    float* R      = (float*)w;  w += (size_t)NN * MIDW * 4;
    float* S      = (float*)w;  w += (size_t)NN * MIDW * 4;

    // 1a) strip masks + counts (adj only)
    k_count<<<NN * NSTRIP / 4, 256, 0, stream>>>(adj, msk, cnt, dflag);
    // 1b) per-row strip offsets
    k_prefix<<<NN / 256, 256, 0, stream>>>(cnt, off, nnz);
    // 1c) fill CSR from masks (xdeg/ydeg streams; no adj re-read)
    k_fill<<<NN * NSTRIP / 4, 256, 0, stream>>>(
        xdeg, ydeg, msk, off, dflag, mlp_w1, mlp_b1, mlp_w2, mlp_b2,
        a_vals, a_cols, rs_part);
    // 1d) colsum partials from CSR (LDS atomics only)
    k_colsum<<<CS_BLOCKS, 256, 0, stream>>>(a_vals, a_cols, nnz, P);
    // 2) degree scales (rowsum from strip partials, colsum from P)
    k_scale2<<<NN / 256, 256, 0, stream>>>(rs_part, P, d_row, d_col);
    // 3) BN-fold precompute
    k_prep<<<1, 512, 0, stream>>>(lin2_w, lin2_b, bn1_g, bn1_b, bn1_m, bn1_v,
                                  bn2_g, bn2_b, bn2_m, bn2_v, Wp, c1, s2g, t2g);
    // 4) W2 = gc1 @ Wp
    k_thin<false, false><<<INS / 16, 256, 0, stream>>>(
        gc1_w, Wp, nullptr, nullptr, W2, INS, HIDW);
    // 5) G = d_col ⊙ ((pe_w + pe_b) @ W2)
    k_thin<true, true><<<NN / 16, 256, 0, stream>>>(
        pe_w, W2, pe_b, d_col, G, NN, INS);
    // 6) mid = Dr·(Â@G) + c1 ; R = d_col ⊙ relu(mid)
    k_spmm64<true><<<NN, 64, 0, stream>>>(
        a_vals, a_cols, nnz, G, d_row, d_col, c1, mid, R);
    // 7) S = Dr·(Â@R)
    k_spmm64<false><<<NN, 64, 0, stream>>>(
        a_vals, a_cols, nnz, R, d_row, d_col, nullptr, S, nullptr);
    // 8) out = BN2(S @ gc3)
    k_out<<<NN / 16, 256, 0, stream>>>(S, gc3_w, s2g, t2g, out);
}

// Round 10
// 156.229 us; speedup vs baseline: 1.2057x; 1.2057x over previous
//
#include <hip/hip_runtime.h>
#include <hip/hip_bf16.h>

#define NN 4096
#define INS 512
#define HIDW 512
#define MIDW 64
#define OUTW 128
#define CAP 384   // per-row nonzero capacity (mean ~205, binomial max ~275)
#define BN_EPS 1e-5f
#define CS_BLOCKS 128
#define CS_ROWS (NN / CS_BLOCKS)   // 32 rows per colsum block
#define NSTRIP 16                  // 256-col strips per row

// ---------------------------------------------------------------------------
// K1a: per-(row,strip) active masks + counts. One wave per 256-col strip.
// Fully parallel: 65536 independent waves, no running offsets.
// ---------------------------------------------------------------------------
__global__ __launch_bounds__(256) void k_count(
    const float* __restrict__ adj,
    unsigned long long* __restrict__ msk, int* __restrict__ cnt,
    int* __restrict__ dflag)
{
    const int t = threadIdx.x;
    const int wave = t >> 6, lane = t & 63;
    const int gw = blockIdx.x * 4 + wave;
    const int i = gw >> 4, s = gw & 15;
    const int colbase = s * 256;
    float4 a4 = *reinterpret_cast<const float4*>(
        adj + (size_t)i * NN + colbase + 4 * lane);
    const float av[4] = {a4.x, a4.y, a4.z, a4.w};
    unsigned long long m[4];
    int total = 0;
    #pragma unroll
    for (int c = 0; c < 4; ++c) {
        int col = colbase + 4 * lane + c;
        bool diag = (col == i);
        bool act = (av[c] != 0.f) || diag;
        if (diag) dflag[i] = (av[c] != 0.f) ? 1 : 0;   // one lane per row hits this
        m[c] = __ballot(act);
        total += __popcll(m[c]);
    }
    if (lane == 0) {
        unsigned long long* mp = msk + (size_t)gw * 4;
        mp[0] = m[0]; mp[1] = m[1]; mp[2] = m[2]; mp[3] = m[3];
        cnt[gw] = total;
    }
}

// ---------------------------------------------------------------------------
// K1b: per-row exclusive prefix over the 16 strip counts
// ---------------------------------------------------------------------------
__global__ __launch_bounds__(256) void k_prefix(
    const int* __restrict__ cnt, int* __restrict__ off, int* __restrict__ nnz)
{
    int i = blockIdx.x * 256 + threadIdx.x;
    int run = 0;
    #pragma unroll
    for (int s = 0; s < NSTRIP; ++s) {
        off[i * NSTRIP + s] = run;
        run += cnt[i * NSTRIP + s];
    }
    nnz[i] = (run < CAP) ? run : CAP;
}

// ---------------------------------------------------------------------------
// K1c: fill CSR. One BLOCK per row: 4 waves x 4 strips stream xdeg/ydeg and
// scatter (col,x,y) into LDS at mask-derived ABSOLUTE positions (no ballots,
// no cross-strip dependence -> all loads pipeline). Then one barrier and a
// dense MLP pass over the ~205 compacted entries (full lane utilization).
// ---------------------------------------------------------------------------
__global__ __launch_bounds__(256) void k_fill(
    const float* __restrict__ xdeg, const float* __restrict__ ydeg,
    const unsigned long long* __restrict__ msk, const int* __restrict__ off,
    const int* __restrict__ nnz, const int* __restrict__ dflag,
    const float* __restrict__ w1, const float* __restrict__ b1,
    const float* __restrict__ w2, const float* __restrict__ b2,
    float* __restrict__ a_vals, int* __restrict__ a_cols,
    float* __restrict__ rowsum)
{
    __shared__ float shb[16], sw1x[16], sw1y[16], sw2[32], sb2[2];
    __shared__ int   scol[CAP];
    __shared__ float sx[CAP];
    __shared__ float sy[CAP];
    __shared__ float swsum[4];
    const int t = threadIdx.x;
    const int wave = t >> 6, lane = t & 63;
    const int i = blockIdx.x;

    if (t < 16) {
        shb[t]  = b1[t] + w1[t];      // fold av==1 weight row into bias
        sw1x[t] = w1[16 + t];
        sw1y[t] = w1[32 + t];
    }
    if (t < 32) sw2[t] = w2[t];
    if (t < 2)  sb2[t] = b2[t];
    __syncthreads();

    const unsigned long long ltmask = (1ULL << lane) - 1ULL;

    // ---- Phase 1: 4 strips per wave; scatter actives into LDS at abs pos ----
    #pragma unroll
    for (int q = 0; q < 4; ++q) {
        const int s = wave * 4 + q;
        const int colbase = s * 256;
        const size_t rbase = (size_t)i * NN + colbase + 4 * lane;
        float4 x4 = *reinterpret_cast<const float4*>(xdeg + rbase);
        float4 y4 = *reinterpret_cast<const float4*>(ydeg + rbase);
        const unsigned long long* mp = msk + ((size_t)i * NSTRIP + s) * 4;
        unsigned long long mm0 = mp[0], mm1 = mp[1], mm2 = mp[2], mm3 = mp[3];
        const int wb = off[i * NSTRIP + s];
        int bases[4];
        bases[0] = 0;
        bases[1] = __popcll(mm0);
        bases[2] = bases[1] + __popcll(mm1);
        bases[3] = bases[2] + __popcll(mm2);
        const unsigned long long mm[4] = {mm0, mm1, mm2, mm3};
        const float xv[4] = {x4.x, x4.y, x4.z, x4.w};
        const float yv[4] = {y4.x, y4.y, y4.z, y4.w};
        #pragma unroll
        for (int c = 0; c < 4; ++c) {
            if ((mm[c] >> lane) & 1ULL) {
                int pos = wb + bases[c] + __popcll(mm[c] & ltmask);
                if (pos < CAP) {
                    scol[pos] = colbase + 4 * lane + c;
                    sx[pos]   = xv[c];
                    sy[pos]   = yv[c];
                }
            }
        }
    }
    __syncthreads();

    // ---- Phase 2: dense MLP over compacted entries ----
    const int n = nnz[i];
    const int hasde = dflag[i];
    float* __restrict__ gv = a_vals + (size_t)i * CAP;
    int*   __restrict__ gc = a_cols + (size_t)i * CAP;
    float local = 0.f;
    for (int p = t; p < n; p += 256) {
        int col = scol[p];
        float x = sx[p], y = sy[p];
        float l0 = sb2[0], l1 = sb2[1];
        #pragma unroll
        for (int w = 0; w < 16; ++w) {
            float hw = fmaf(x, sw1x[w], shb[w]);
            hw = fmaf(y, sw1y[w], hw);
            hw = fmaxf(hw, 0.f);
            l0 = fmaf(hw, sw2[2 * w],     l0);
            l1 = fmaf(hw, sw2[2 * w + 1], l1);
        }
        float v = 1.f / (1.f + __expf(l0 - l1));   // softmax(...)[1]
        if (col == i) v = hasde ? (v + 1.f) : 1.f;
        gc[p] = col;
        gv[p] = v;
        local += v;
    }
    #pragma unroll
    for (int o = 32; o >= 1; o >>= 1)
        local += __shfl_down(local, o, 64);
    if (lane == 0) swsum[wave] = local;
    __syncthreads();
    if (t == 0)
        rowsum[i] = swsum[0] + swsum[1] + swsum[2] + swsum[3];
}

// ---------------------------------------------------------------------------
// K1d: column sums of the CSR, hierarchical (LDS atomics -> dense partials)
// ---------------------------------------------------------------------------
__global__ __launch_bounds__(256) void k_colsum(
    const float* __restrict__ a_vals, const int* __restrict__ a_cols,
    const int* __restrict__ nnz, float* __restrict__ P)
{
    __shared__ float ls[NN];
    const int t = threadIdx.x;
    const int b = blockIdx.x;
    for (int j = t; j < NN; j += 256) ls[j] = 0.f;
    __syncthreads();
    const int r0 = b * CS_ROWS;
    for (int r = r0; r < r0 + CS_ROWS; ++r) {
        const int n = nnz[r];
        const float* __restrict__ vr = a_vals + (size_t)r * CAP;
        const int*   __restrict__ cr = a_cols + (size_t)r * CAP;
        for (int p = t; p < n; p += 256)
            atomicAdd(&ls[cr[p]], vr[p]);
    }
    __syncthreads();
    for (int j = t; j < NN; j += 256)
        P[(size_t)b * NN + j] = ls[j];
}

// ---------------------------------------------------------------------------
// K2: reduce partials -> degree scale factors
// ---------------------------------------------------------------------------
__global__ __launch_bounds__(256) void k_scale2(
    const float* __restrict__ rowsum, const float* __restrict__ P,
    float* __restrict__ d_row, float* __restrict__ d_col)
{
    int j = blockIdx.x * 256 + threadIdx.x;
    float r = rowsum[j];
    d_row[j] = (r > 0.f) ? 1.f / sqrtf(r) : 0.f;
    float c = 0.f;
    for (int b = 0; b < CS_BLOCKS; ++b)
        c += P[(size_t)b * NN + j];
    d_col[j] = (c > 0.f) ? 1.f / sqrtf(c) : 0.f;
}

// ---------------------------------------------------------------------------
// K3: prep — Wp = s1 ⊙rows lin2_w ;  c1 = t1@lin2_w + lin2_b ;  s2/t2 for BN2
// ---------------------------------------------------------------------------
__global__ __launch_bounds__(512) void k_prep(
    const float* __restrict__ lin2_w, const float* __restrict__ lin2_b,
    const float* __restrict__ bn1_g, const float* __restrict__ bn1_b,
    const float* __restrict__ bn1_m, const float* __restrict__ bn1_v,
    const float* __restrict__ bn2_g, const float* __restrict__ bn2_b,
    const float* __restrict__ bn2_m, const float* __restrict__ bn2_v,
    float* __restrict__ Wp, float* __restrict__ c1,
    float* __restrict__ s2g, float* __restrict__ t2g)
{
    __shared__ float t1s[HIDW];
    const int t = threadIdx.x;
    {
        int h = t;
        float s1 = bn1_g[h] * rsqrtf(bn1_v[h] + BN_EPS);
        t1s[h] = bn1_b[h] - bn1_m[h] * s1;
        for (int m = 0; m < MIDW; ++m)
            Wp[(size_t)h * MIDW + m] = s1 * lin2_w[(size_t)h * MIDW + m];
    }
    __syncthreads();
    if (t < MIDW) {
        float acc = lin2_b[t];
        for (int h = 0; h < HIDW; ++h)
            acc = fmaf(t1s[h], lin2_w[(size_t)h * MIDW + t], acc);
        c1[t] = acc;
    } else if (t >= 64 && t < 64 + OUTW) {
        int j = t - 64;
        float s2 = bn2_g[j] * rsqrtf(bn2_v[j] + BN_EPS);
        s2g[j] = s2;
        t2g[j] = bn2_b[j] - bn2_m[j] * s2;
    }
}

// ---------------------------------------------------------------------------
// K4: thin GEMM  C[M x 64] = (A[M x K] (+abias along k)) @ B[K x 64], epi rowscale
// ---------------------------------------------------------------------------
template <bool ABIAS, bool ROWSCALE>
__global__ __launch_bounds__(256) void k_thin(
    const float* __restrict__ A, const float* __restrict__ B,
    const float* __restrict__ abias, const float* __restrict__ rscale,
    float* __restrict__ C, int M, int K)
{
    __shared__ float As[64][20];   // [k][r], stride 20 -> b128-aligned reads
    __shared__ float Bs[64][64];
    const int t = threadIdx.x;
    const int bm = blockIdx.x * 16;
    const int col = t & 63, rg = t >> 6;

    float acc[4] = {0.f, 0.f, 0.f, 0.f};

    for (int k0 = 0; k0 < K; k0 += 64) {
        #pragma unroll
        for (int l = 0; l < 4; ++l) {
            int e = t + l * 256;
            int r = e >> 6, k = e & 63;
            float v = A[(size_t)(bm + r) * K + k0 + k];
            if (ABIAS) v += abias[k0 + k];
            As[k][r] = v;
        }
        #pragma unroll
        for (int l = 0; l < 16; ++l) {
            int e = t + l * 256;
            int k = e >> 6, n = e & 63;
            Bs[k][n] = B[(size_t)(k0 + k) * 64 + n];
        }
        __syncthreads();
        #pragma unroll
        for (int k = 0; k < 64; ++k) {
            float4 a4 = *reinterpret_cast<const float4*>(&As[k][rg * 4]);
            float b = Bs[k][col];
            acc[0] = fmaf(a4.x, b, acc[0]);
            acc[1] = fmaf(a4.y, b, acc[1]);
            acc[2] = fmaf(a4.z, b, acc[2]);
            acc[3] = fmaf(a4.w, b, acc[3]);
        }
        __syncthreads();
    }

    #pragma unroll
    for (int u = 0; u < 4; ++u) {
        int r = bm + rg * 4 + u;
        float x = acc[u];
        if (ROWSCALE) x *= rscale[r];
        C[(size_t)r * 64 + col] = x;
    }
}

// ---------------------------------------------------------------------------
// K5: 64-wide SpMM, 1 wave per row, 2 edges per load-inst (512 B/inst).
// ---------------------------------------------------------------------------
template <bool WITH_MID>
__global__ __launch_bounds__(64) void k_spmm64(
    const float* __restrict__ a_vals, const int* __restrict__ a_cols,
    const int* __restrict__ nnz, const float* __restrict__ X,
    const float* __restrict__ d_row, const float* __restrict__ d_col,
    const float* __restrict__ c1,
    float* __restrict__ O1, float* __restrict__ O2)
{
    __shared__ float sv[CAP];
    __shared__ int   scl[CAP];
    const int i = blockIdx.x;
    const int lane = threadIdx.x;
    const int n = nnz[i];
    const int n8 = (n + 7) & ~7;
    const float* __restrict__ vrow = a_vals + (size_t)i * CAP;
    const int*   __restrict__ crow = a_cols + (size_t)i * CAP;

    for (int p = lane; p < n8; p += 64) {
        bool ok = p < n;
        sv[p]  = ok ? vrow[p] : 0.f;
        scl[p] = ok ? crow[p] : 0;
    }
    __syncthreads();

    const int eh = lane >> 5;
    const int lc = lane & 31;
    const int npairs = n8 >> 1;

    float a0 = 0.f, a1 = 0.f;
    for (int q = 0; q < npairs; q += 4) {
        #pragma unroll
        for (int j = 0; j < 4; ++j) {
            int p = 2 * (q + j) + eh;
            float v = sv[p];
            int c = scl[p];
            float2 x = *reinterpret_cast<const float2*>(X + (size_t)c * 64 + 2 * lc);
            a0 = fmaf(v, x.x, a0);
            a1 = fmaf(v, x.y, a1);
        }
    }
    a0 += __shfl_xor(a0, 32);
    a1 += __shfl_xor(a1, 32);

    if (lane < 32) {
        float dr = d_row[i];
        if (WITH_MID) {
            float dc = d_col[i];
            float m0 = fmaf(a0, dr, c1[2 * lc]);
            float m1 = fmaf(a1, dr, c1[2 * lc + 1]);
            *reinterpret_cast<float2*>(O1 + (size_t)i * 64 + 2 * lc) =
                make_float2(m0, m1);
            *reinterpret_cast<float2*>(O2 + (size_t)i * 64 + 2 * lc) =
                make_float2(dc * fmaxf(m0, 0.f), dc * fmaxf(m1, 0.f));
        } else {
            *reinterpret_cast<float2*>(O1 + (size_t)i * 64 + 2 * lc) =
                make_float2(a0 * dr, a1 * dr);
        }
    }
}

// ---------------------------------------------------------------------------
// K6: out[4096x128] = (S[4096x64] @ gc3[64x128]) * s2 + t2
// ---------------------------------------------------------------------------
__global__ __launch_bounds__(256) void k_out(
    const float* __restrict__ S, const float* __restrict__ gc3,
    const float* __restrict__ s2g, const float* __restrict__ t2g,
    float* __restrict__ out)
{
    __shared__ float Ss[64][20];
    __shared__ float Gs[64][128];
    const int t = threadIdx.x;
    const int bm = blockIdx.x * 16;

    {
        int r = t >> 4, c4 = (t & 15) * 4;
        float4 v = *reinterpret_cast<const float4*>(S + (size_t)(bm + r) * 64 + c4);
        Ss[c4 + 0][r] = v.x; Ss[c4 + 1][r] = v.y;
        Ss[c4 + 2][r] = v.z; Ss[c4 + 3][r] = v.w;
    }
    #pragma unroll
    for (int l = 0; l < 32; ++l) {
        int e = t + l * 256;
        Gs[e >> 7][e & 127] = gc3[e];
    }
    __syncthreads();

    const int j = t & 127;
    const int r0 = (t >> 7) * 8;
    float acc[8] = {};
    #pragma unroll
    for (int k = 0; k < 64; ++k) {
        float g = Gs[k][j];
        float4 a = *reinterpret_cast<const float4*>(&Ss[k][r0]);
        float4 b = *reinterpret_cast<const float4*>(&Ss[k][r0 + 4]);
        acc[0] = fmaf(a.x, g, acc[0]); acc[1] = fmaf(a.y, g, acc[1]);
        acc[2] = fmaf(a.z, g, acc[2]); acc[3] = fmaf(a.w, g, acc[3]);
        acc[4] = fmaf(b.x, g, acc[4]); acc[5] = fmaf(b.y, g, acc[5]);
        acc[6] = fmaf(b.z, g, acc[6]); acc[7] = fmaf(b.w, g, acc[7]);
    }
    float s2 = s2g[j], t2 = t2g[j];
    #pragma unroll
    for (int u = 0; u < 8; ++u)
        out[(size_t)(bm + r0 + u) * 128 + j] = fmaf(acc[u], s2, t2);
}

// ---------------------------------------------------------------------------
extern "C" void kernel_launch(void* const* d_in, const int* in_sizes, int n_in,
                              void* d_out, int out_size, void* d_ws, size_t ws_size,
                              hipStream_t stream) {
    const float* adj    = (const float*)d_in[0];
    const float* xdeg   = (const float*)d_in[1];
    const float* ydeg   = (const float*)d_in[2];
    const float* mlp_w1 = (const float*)d_in[3];
    const float* mlp_b1 = (const float*)d_in[4];
    const float* mlp_w2 = (const float*)d_in[5];
    const float* mlp_b2 = (const float*)d_in[6];
    const float* pe_w   = (const float*)d_in[7];
    const float* pe_b   = (const float*)d_in[8];
    const float* gc1_w  = (const float*)d_in[9];
    const float* lin2_w = (const float*)d_in[10];
    const float* lin2_b = (const float*)d_in[11];
    const float* gc3_w  = (const float*)d_in[12];
    const float* bn1_g  = (const float*)d_in[13];
    const float* bn1_b  = (const float*)d_in[14];
    const float* bn1_m  = (const float*)d_in[15];
    const float* bn1_v  = (const float*)d_in[16];
    const float* bn2_g  = (const float*)d_in[17];
    const float* bn2_b  = (const float*)d_in[18];
    const float* bn2_m  = (const float*)d_in[19];
    const float* bn2_v  = (const float*)d_in[20];

    float* out = (float*)d_out;                 // [NN * OUTW]
    float* mid = out + (size_t)NN * OUTW;       // [NN * MIDW]

    char* w = (char*)d_ws;
    float* a_vals = (float*)w;  w += (size_t)NN * CAP * 4;
    int*   a_cols = (int*)w;    w += (size_t)NN * CAP * 4;
    int*   nnz    = (int*)w;    w += (size_t)NN * 4;
    unsigned long long* msk = (unsigned long long*)w; w += (size_t)NN * NSTRIP * 4 * 8;
    int*   cnt    = (int*)w;    w += (size_t)NN * NSTRIP * 4;
    int*   off    = (int*)w;    w += (size_t)NN * NSTRIP * 4;
    int*   dflag  = (int*)w;    w += (size_t)NN * 4;
    float* rowsum = (float*)w;  w += (size_t)NN * 4;
    float* d_row  = (float*)w;  w += (size_t)NN * 4;
    float* d_col  = (float*)w;  w += (size_t)NN * 4;
    float* P      = (float*)w;  w += (size_t)CS_BLOCKS * NN * 4;
    float* Wp     = (float*)w;  w += (size_t)HIDW * MIDW * 4;
    float* W2     = (float*)w;  w += (size_t)INS * MIDW * 4;
    float* c1     = (float*)w;  w += 256;
    float* s2g    = (float*)w;  w += 512;
    float* t2g    = (float*)w;  w += 512;
    float* G      = (float*)w;  w += (size_t)NN * MIDW * 4;
    float* R      = (float*)w;  w += (size_t)NN * MIDW * 4;
    float* S      = (float*)w;  w += (size_t)NN * MIDW * 4;

    // 1a) strip masks + counts (adj only)
    k_count<<<NN * NSTRIP / 4, 256, 0, stream>>>(adj, msk, cnt, dflag);
    // 1b) per-row strip offsets
    k_prefix<<<NN / 256, 256, 0, stream>>>(cnt, off, nnz);
    // 1c) fill CSR: block per row, compact into LDS, then dense MLP
    k_fill<<<NN, 256, 0, stream>>>(
        xdeg, ydeg, msk, off, nnz, dflag, mlp_w1, mlp_b1, mlp_w2, mlp_b2,
        a_vals, a_cols, rowsum);
    // 1d) colsum partials from CSR (LDS atomics only)
    k_colsum<<<CS_BLOCKS, 256, 0, stream>>>(a_vals, a_cols, nnz, P);
    // 2) degree scales
    k_scale2<<<NN / 256, 256, 0, stream>>>(rowsum, P, d_row, d_col);
    // 3) BN-fold precompute
    k_prep<<<1, 512, 0, stream>>>(lin2_w, lin2_b, bn1_g, bn1_b, bn1_m, bn1_v,
                                  bn2_g, bn2_b, bn2_m, bn2_v, Wp, c1, s2g, t2g);
    // 4) W2 = gc1 @ Wp
    k_thin<false, false><<<INS / 16, 256, 0, stream>>>(
        gc1_w, Wp, nullptr, nullptr, W2, INS, HIDW);
    // 5) G = d_col ⊙ ((pe_w + pe_b) @ W2)
    k_thin<true, true><<<NN / 16, 256, 0, stream>>>(
        pe_w, W2, pe_b, d_col, G, NN, INS);
    // 6) mid = Dr·(Â@G) + c1 ; R = d_col ⊙ relu(mid)
    k_spmm64<true><<<NN, 64, 0, stream>>>(
        a_vals, a_cols, nnz, G, d_row, d_col, c1, mid, R);
    // 7) S = Dr·(Â@R)
    k_spmm64<false><<<NN, 64, 0, stream>>>(
        a_vals, a_cols, nnz, R, d_row, d_col, nullptr, S, nullptr);
    // 8) out = BN2(S @ gc3)
    k_out<<<NN / 16, 256, 0, stream>>>(S, gc3_w, s2g, t2g, out);
}